// Round 2
// baseline (2668.034 us; speedup 1.0000x reference)
//
#include <hip/hip_runtime.h>
#include <math.h>

#define N 8192
#define FIN 512
#define FOUT 256
#define NEGV (-9e15f)

#define BM 32
#define BN 64
#define TPB 256
#define QPAD 260   // LDS row stride for Wh tiles (keeps 16B align, breaks bank patterns)
#define PTS 36     // Pt row stride

// ---------------- kernel 0: mui softmax + derived params ----------------
__global__ void params_kernel(const float* __restrict__ Mui, float* __restrict__ params) {
    if (threadIdx.x == 0) {
        float m = Mui[0];
        for (int i = 1; i < 6; ++i) m = fmaxf(m, Mui[i]);
        float e[6], s = 0.f;
        for (int i = 0; i < 6; ++i) { e[i] = expf(Mui[i] - m); s += e[i]; }
        float mui[6];
        for (int i = 0; i < 6; ++i) mui[i] = e[i] / s;
        params[0] = mui[0] + mui[1] + mui[2] + mui[3];            // a (G coefficient)
        params[1] = 0.5f * (mui[0] + mui[1]) + 1.0f * (mui[2] + mui[3]); // additive const
        params[2] = 256.0f * mui[4];                               // D*mui4
        params[3] = 256.0f * mui[5];                               // D*mui5
    }
}

// ---------------- kernel 1: Wh = h @ W  (8192x512x256 f32) ----------------
#define GK 16
__global__ __launch_bounds__(256) void wh_gemm(const float* __restrict__ A,
                                               const float* __restrict__ B,
                                               float* __restrict__ C) {
    __shared__ float As[GK][68];
    __shared__ float Bs[GK][68];
    const int tid = threadIdx.x;
    const int m0 = blockIdx.y * 64, n0 = blockIdx.x * 64;
    const int tx = tid & 15, ty = tid >> 4;
    const int arow = tid >> 2, akk = (tid & 3) * 4;
    const int brow = tid >> 4, bnn = (tid & 15) * 4;
    float acc[4][4] = {};
    for (int k0 = 0; k0 < FIN; k0 += GK) {
        float4 av = *(const float4*)&A[(m0 + arow) * FIN + k0 + akk];
        float4 bv = *(const float4*)&B[(k0 + brow) * FOUT + n0 + bnn];
        As[akk + 0][arow] = av.x; As[akk + 1][arow] = av.y;
        As[akk + 2][arow] = av.z; As[akk + 3][arow] = av.w;
        *(float4*)&Bs[brow][bnn] = bv;
        __syncthreads();
#pragma unroll
        for (int k = 0; k < GK; ++k) {
            float4 a = *(const float4*)&As[k][4 * ty];
            float4 b = *(const float4*)&Bs[k][4 * tx];
            float ar[4] = {a.x, a.y, a.z, a.w};
            float br[4] = {b.x, b.y, b.z, b.w};
#pragma unroll
            for (int i = 0; i < 4; ++i)
#pragma unroll
                for (int j = 0; j < 4; ++j)
                    acc[i][j] = fmaf(ar[i], br[j], acc[i][j]);
        }
        __syncthreads();
    }
#pragma unroll
    for (int i = 0; i < 4; ++i) {
        float4 v = make_float4(acc[i][0], acc[i][1], acc[i][2], acc[i][3]);
        *(float4*)&C[(m0 + 4 * ty + i) * FOUT + n0 + 4 * tx] = v;
    }
}

// ---------------- kernel 2: per-row/col exp factors ----------------
__global__ void factors_kernel(const float* __restrict__ Wh, const float* __restrict__ params,
                               float* __restrict__ x1, float* __restrict__ x2,
                               float* __restrict__ w1, float* __restrict__ w2) {
    int i = blockIdx.x * blockDim.x + threadIdx.x;
    if (i < N) {
        float t = Wh[i * FOUT + 1];
        float t1 = t * t;
        float p4 = params[2], p5 = params[3];
        x1[i] = expf(0.5f * t1);
        x2[i] = expf(t1);
        w1[i] = p4 * expf(-0.5f * t1);
        w2[i] = p5 * expf(-t1);
    }
}

// ---------------- kernel 3: fused logits + masked online softmax + PV ----------------
// NOTE: macro parameter names must not collide with member names x/y/z/w
// (preprocessor substitutes after '.' too).
#define DOT4_ACC(ss, aa, bb) ss = fmaf((aa).x,(bb).x, fmaf((aa).y,(bb).y, fmaf((aa).z,(bb).z, fmaf((aa).w,(bb).w,(ss)))))
#define AXPY4(oo, pp, vv) { (oo).x = fmaf((pp),(vv).x,(oo).x); (oo).y = fmaf((pp),(vv).y,(oo).y); \
                            (oo).z = fmaf((pp),(vv).z,(oo).z); (oo).w = fmaf((pp),(vv).w,(oo).w); }

__global__ __launch_bounds__(TPB) void attn_kernel(
    const float* __restrict__ Wh, const float* __restrict__ x1, const float* __restrict__ x2,
    const float* __restrict__ w1, const float* __restrict__ w2,
    const float* __restrict__ params, const int* __restrict__ adj,
    float* __restrict__ out)
{
    extern __shared__ float smem[];
    float* Whq  = smem;                 // [BM][QPAD]
    float* Whk  = Whq + BM * QPAD;      // [BN][QPAD]
    float* Pt   = Whk + BN * QPAD;      // [BN][PTS] (P transposed: [col][row])
    float* mrow = Pt + BN * PTS;        // [BM]
    float* lrow = mrow + BM;
    float* alph = lrow + BM;
    float* w1q  = alph + BM;
    float* w2q  = w1q + BM;
    float* x1k  = w2q + BM;             // [BN]
    float* x2k  = x1k + BN;

    const int tid  = threadIdx.x;
    const int row0 = blockIdx.x * BM;
    const float aCoef = params[0], cAdd = params[1];

    // load Whq tile (BM x 256)
#pragma unroll
    for (int t = 0; t < 8; ++t) {
        int f4 = tid + t * TPB;         // 0..2047
        int r = f4 >> 6, c4 = f4 & 63;
        float4 v = *(const float4*)&Wh[(row0 + r) * FOUT + c4 * 4];
        *(float4*)&Whq[r * QPAD + c4 * 4] = v;
    }
    if (tid < BM) {
        w1q[tid] = w1[row0 + tid];
        w2q[tid] = w2[row0 + tid];
        mrow[tid] = -INFINITY;
        lrow[tid] = 0.f;
    }

    // S-phase mapping: rows {qr,qr+1}, cols {qc..qc+3}
    const int qr = (tid >> 4) * 2;
    const int qc = (tid & 15) * 4;
    // PV mapping: rows {pr..pr+3}, cols {pc..pc+7}
    const int pr = (tid >> 5) * 4;
    const int pc = (tid & 31) * 8;

    float4 O[4][2];
#pragma unroll
    for (int i = 0; i < 4; ++i) { O[i][0] = make_float4(0,0,0,0); O[i][1] = make_float4(0,0,0,0); }

    __syncthreads();

    for (int j0 = 0; j0 < N; j0 += BN) {
        // stage Whk tile (BN x 256)
#pragma unroll
        for (int t = 0; t < 16; ++t) {
            int f4 = tid + t * TPB;     // 0..4095
            int r = f4 >> 6, c4 = f4 & 63;
            float4 v = *(const float4*)&Wh[(j0 + r) * FOUT + c4 * 4];
            *(float4*)&Whk[r * QPAD + c4 * 4] = v;
        }
        if (tid < BN) {
            x1k[tid] = x1[j0 + tid];
            x2k[tid] = x2[j0 + tid];
        }
        __syncthreads();

        // prefetch adj tile (2 rows x 4 cols per thread)
        int4 ad0 = *(const int4*)&adj[(row0 + qr) * N + j0 + qc];
        int4 ad1 = *(const int4*)&adj[(row0 + qr + 1) * N + j0 + qc];

        // S = Whq . Whk^T over K=256
        float s[2][4] = {};
        {
            const float4* a0p = (const float4*)&Whq[qr * QPAD];
            const float4* a1p = (const float4*)&Whq[(qr + 1) * QPAD];
            const float4* b0p = (const float4*)&Whk[(qc + 0) * QPAD];
            const float4* b1p = (const float4*)&Whk[(qc + 1) * QPAD];
            const float4* b2p = (const float4*)&Whk[(qc + 2) * QPAD];
            const float4* b3p = (const float4*)&Whk[(qc + 3) * QPAD];
#pragma unroll 2
            for (int k = 0; k < 64; ++k) {
                float4 a0 = a0p[k], a1 = a1p[k];
                float4 b0 = b0p[k], b1 = b1p[k], b2 = b2p[k], b3 = b3p[k];
                DOT4_ACC(s[0][0], a0, b0); DOT4_ACC(s[0][1], a0, b1);
                DOT4_ACC(s[0][2], a0, b2); DOT4_ACC(s[0][3], a0, b3);
                DOT4_ACC(s[1][0], a1, b0); DOT4_ACC(s[1][1], a1, b1);
                DOT4_ACC(s[1][2], a1, b2); DOT4_ACC(s[1][3], a1, b3);
            }
        }

        // logits + mask
        float e[2][4];
        const int am[2][4] = {{ad0.x, ad0.y, ad0.z, ad0.w}, {ad1.x, ad1.y, ad1.z, ad1.w}};
        float w1r[2] = {w1q[qr], w1q[qr + 1]};
        float w2r[2] = {w2q[qr], w2q[qr + 1]};
#pragma unroll
        for (int r = 0; r < 2; ++r)
#pragma unroll
            for (int c = 0; c < 4; ++c) {
                float ev = fmaf(aCoef, s[r][c], cAdd);
                ev = fmaf(w1r[r], x1k[qc + c], ev);
                ev = fmaf(w2r[r], x2k[qc + c], ev);
                e[r][c] = (am[r][c] > 0) ? ev : NEGV;
            }

        // per-row max over the 64-col tile (16 threads share a row pair)
        float mx[2];
#pragma unroll
        for (int r = 0; r < 2; ++r)
            mx[r] = fmaxf(fmaxf(e[r][0], e[r][1]), fmaxf(e[r][2], e[r][3]));
#pragma unroll
        for (int off = 1; off < 16; off <<= 1) {
            mx[0] = fmaxf(mx[0], __shfl_xor(mx[0], off, 64));
            mx[1] = fmaxf(mx[1], __shfl_xor(mx[1], off, 64));
        }
        float newm[2], al[2];
#pragma unroll
        for (int r = 0; r < 2; ++r) {
            float oldm = mrow[qr + r];
            newm[r] = fmaxf(oldm, mx[r]);
            al[r] = expf(oldm - newm[r]);   // exp(-inf)=0 first tile
        }
        float p[2][4], sm[2];
#pragma unroll
        for (int r = 0; r < 2; ++r) {
            sm[r] = 0.f;
#pragma unroll
            for (int c = 0; c < 4; ++c) { p[r][c] = expf(e[r][c] - newm[r]); sm[r] += p[r][c]; }
        }
#pragma unroll
        for (int off = 1; off < 16; off <<= 1) {
            sm[0] += __shfl_xor(sm[0], off, 64);
            sm[1] += __shfl_xor(sm[1], off, 64);
        }
        // write P transposed
#pragma unroll
        for (int r = 0; r < 2; ++r)
#pragma unroll
            for (int c = 0; c < 4; ++c)
                Pt[(qc + c) * PTS + qr + r] = p[r][c];
        if ((tid & 15) == 0) {
#pragma unroll
            for (int r = 0; r < 2; ++r) {
                mrow[qr + r] = newm[r];
                lrow[qr + r] = fmaf(al[r], lrow[qr + r], sm[r]);
                alph[qr + r] = al[r];
            }
        }
        __syncthreads();

        // PV: O = alpha*O + P @ Whk
        float alv[4];
#pragma unroll
        for (int i = 0; i < 4; ++i) alv[i] = alph[pr + i];
#pragma unroll
        for (int i = 0; i < 4; ++i) {
            O[i][0].x *= alv[i]; O[i][0].y *= alv[i]; O[i][0].z *= alv[i]; O[i][0].w *= alv[i];
            O[i][1].x *= alv[i]; O[i][1].y *= alv[i]; O[i][1].z *= alv[i]; O[i][1].w *= alv[i];
        }
#pragma unroll 2
        for (int j = 0; j < BN; ++j) {
            float4 pv  = *(const float4*)&Pt[j * PTS + pr];
            float4 wv0 = *(const float4*)&Whk[j * QPAD + pc];
            float4 wv1 = *(const float4*)&Whk[j * QPAD + pc + 4];
            AXPY4(O[0][0], pv.x, wv0); AXPY4(O[0][1], pv.x, wv1);
            AXPY4(O[1][0], pv.y, wv0); AXPY4(O[1][1], pv.y, wv1);
            AXPY4(O[2][0], pv.z, wv0); AXPY4(O[2][1], pv.z, wv1);
            AXPY4(O[3][0], pv.w, wv0); AXPY4(O[3][1], pv.w, wv1);
        }
        __syncthreads();
    }

    // epilogue: normalize, ELU, store
    float linv[4];
#pragma unroll
    for (int i = 0; i < 4; ++i) linv[i] = 1.0f / lrow[pr + i];
#pragma unroll
    for (int i = 0; i < 4; ++i) {
        float4 v0 = O[i][0], v1 = O[i][1];
        v0.x *= linv[i]; v0.y *= linv[i]; v0.z *= linv[i]; v0.w *= linv[i];
        v1.x *= linv[i]; v1.y *= linv[i]; v1.z *= linv[i]; v1.w *= linv[i];
        v0.x = v0.x > 0.f ? v0.x : expm1f(v0.x);
        v0.y = v0.y > 0.f ? v0.y : expm1f(v0.y);
        v0.z = v0.z > 0.f ? v0.z : expm1f(v0.z);
        v0.w = v0.w > 0.f ? v0.w : expm1f(v0.w);
        v1.x = v1.x > 0.f ? v1.x : expm1f(v1.x);
        v1.y = v1.y > 0.f ? v1.y : expm1f(v1.y);
        v1.z = v1.z > 0.f ? v1.z : expm1f(v1.z);
        v1.w = v1.w > 0.f ? v1.w : expm1f(v1.w);
        *(float4*)&out[(row0 + pr + i) * FOUT + pc]     = v0;
        *(float4*)&out[(row0 + pr + i) * FOUT + pc + 4] = v1;
    }
}

// ---------------- launch ----------------
extern "C" void kernel_launch(void* const* d_in, const int* in_sizes, int n_in,
                              void* d_out, int out_size, void* d_ws, size_t ws_size,
                              hipStream_t stream) {
    const float* h   = (const float*)d_in[0];
    const float* W   = (const float*)d_in[1];
    const float* Mui = (const float*)d_in[2];
    const int*   adj = (const int*)d_in[3];
    float* out = (float*)d_out;

    float* ws = (float*)d_ws;
    float* Wh     = ws;                    // 8192*256
    float* x1     = Wh + N * FOUT;
    float* x2     = x1 + N;
    float* w1     = x2 + N;
    float* w2     = w1 + N;
    float* params = w2 + N;                // 8 floats

    params_kernel<<<1, 64, 0, stream>>>(Mui, params);
    wh_gemm<<<dim3(FOUT / 64, N / 64), 256, 0, stream>>>(h, W, Wh);
    factors_kernel<<<N / 256, 256, 0, stream>>>(Wh, params, x1, x2, w1, w2);

    const int smem_bytes = (BM * QPAD + BN * QPAD + BN * PTS + 5 * BM + 2 * BN) * sizeof(float);
    hipFuncSetAttribute((const void*)attn_kernel,
                        hipFuncAttributeMaxDynamicSharedMemorySize, smem_bytes);
    attn_kernel<<<N / BM, TPB, smem_bytes, stream>>>(Wh, x1, x2, w1, w2, params, adj, out);
    (void)n_in; (void)in_sizes; (void)out_size; (void)ws_size;
}

// Round 3
// 949.873 us; speedup vs baseline: 2.8088x; 2.8088x over previous
//
#include <hip/hip_runtime.h>
#include <math.h>

#define N 8192
#define FIN 512
#define FOUT 256
#define NEGV (-9e15f)
#define NCAND 64

// ---------------- kernel 0: mui softmax + derived params (+zero ctrl) ----------------
__global__ void params_kernel(const float* __restrict__ Mui, float* __restrict__ params,
                              unsigned* __restrict__ gmaxbits) {
    if (threadIdx.x == 0) {
        float m = Mui[0];
        for (int i = 1; i < 6; ++i) m = fmaxf(m, Mui[i]);
        float e[6], s = 0.f;
        for (int i = 0; i < 6; ++i) { e[i] = expf(Mui[i] - m); s += e[i]; }
        float mui[6];
        for (int i = 0; i < 6; ++i) mui[i] = e[i] / s;
        params[0] = mui[0] + mui[1] + mui[2] + mui[3];                    // a (G coefficient)
        params[1] = 0.5f * (mui[0] + mui[1]) + 1.0f * (mui[2] + mui[3]); // additive const
        params[2] = 256.0f * mui[4];                                      // D*mui4
        params[3] = 256.0f * mui[5];                                      // D*mui5
        *gmaxbits = 0u;                                                   // re-init every call
    }
}

// ---------------- kernel 1: Wh = h @ W  (8192x512x256 f32) ----------------
#define GK 16
__global__ __launch_bounds__(256) void wh_gemm(const float* __restrict__ A,
                                               const float* __restrict__ B,
                                               float* __restrict__ C) {
    __shared__ float As[GK][68];
    __shared__ float Bs[GK][68];
    const int tid = threadIdx.x;
    const int m0 = blockIdx.y * 64, n0 = blockIdx.x * 64;
    const int tx = tid & 15, ty = tid >> 4;
    const int arow = tid >> 2, akk = (tid & 3) * 4;
    const int brow = tid >> 4, bnn = (tid & 15) * 4;
    float acc[4][4] = {};
    for (int k0 = 0; k0 < FIN; k0 += GK) {
        float4 av = *(const float4*)&A[(m0 + arow) * FIN + k0 + akk];
        float4 bv = *(const float4*)&B[(k0 + brow) * FOUT + n0 + bnn];
        As[akk + 0][arow] = av.x; As[akk + 1][arow] = av.y;
        As[akk + 2][arow] = av.z; As[akk + 3][arow] = av.w;
        *(float4*)&Bs[brow][bnn] = bv;
        __syncthreads();
#pragma unroll
        for (int k = 0; k < GK; ++k) {
            float4 a = *(const float4*)&As[k][4 * ty];
            float4 b = *(const float4*)&Bs[k][4 * tx];
            float ar[4] = {a.x, a.y, a.z, a.w};
            float br[4] = {b.x, b.y, b.z, b.w};
#pragma unroll
            for (int i = 0; i < 4; ++i)
#pragma unroll
                for (int j = 0; j < 4; ++j)
                    acc[i][j] = fmaf(ar[i], br[j], acc[i][j]);
        }
        __syncthreads();
    }
#pragma unroll
    for (int i = 0; i < 4; ++i) {
        float4 v = make_float4(acc[i][0], acc[i][1], acc[i][2], acc[i][3]);
        *(float4*)&C[(m0 + 4 * ty + i) * FOUT + n0 + 4 * tx] = v;
    }
}

// ---------------- kernel 2: per-row factors, t1, row norms, global max norm ----------------
__global__ __launch_bounds__(64) void factors2_kernel(
    const float* __restrict__ Wh, const float* __restrict__ params,
    float* __restrict__ t1a, float* __restrict__ x1, float* __restrict__ x2,
    float* __restrict__ w1, float* __restrict__ w2,
    float* __restrict__ nrm, unsigned* __restrict__ gmaxbits) {
    int i = blockIdx.x;
    int l = threadIdx.x;
    float4 v = ((const float4*)&Wh[i * FOUT])[l];
    float s = v.x * v.x + v.y * v.y + v.z * v.z + v.w * v.w;
#pragma unroll
    for (int off = 1; off < 64; off <<= 1) s += __shfl_xor(s, off, 64);
    if (l == 0) {
        float nr = sqrtf(s);
        nrm[i] = nr;
        atomicMax(gmaxbits, __float_as_uint(nr));   // nr > 0 -> bit-monotone
        float t = Wh[i * FOUT + 1];
        float t1 = t * t;                            // exact same expr as verified R2 kernel
        t1a[i] = t1;
        x1[i] = expf(0.5f * t1);
        x2[i] = expf(t1);
        w1[i] = params[2] * expf(-0.5f * t1);
        w2[i] = params[3] * expf(-t1);
    }
}

// ---------------- kernel 3: top-64 t1 columns (single block) ----------------
__global__ __launch_bounds__(1024) void topk_kernel(
    const float* __restrict__ t1a, const float* __restrict__ x1, const float* __restrict__ x2,
    int* __restrict__ cidx, float* __restrict__ ct1, float* __restrict__ cx1,
    float* __restrict__ cx2, float* __restrict__ ubx, int* __restrict__ hardcnt) {
    __shared__ float v[N];
    __shared__ float wvv[16];
    __shared__ int wii[16];
    __shared__ int bi_s;
    int t = threadIdx.x;
    for (int k = t; k < N; k += 1024) v[k] = t1a[k];
    if (t == 0) *hardcnt = 0;
    __syncthreads();
    for (int r = 0; r < NCAND; ++r) {
        float bestv = -1.f; int besti = 0;          // t1 >= 0, removed = -2
        for (int k = t; k < N; k += 1024) {
            float x = v[k];
            if (x > bestv) { bestv = x; besti = k; }
        }
#pragma unroll
        for (int off = 1; off < 64; off <<= 1) {
            float ov = __shfl_xor(bestv, off, 64);
            int   oi = __shfl_xor(besti, off, 64);
            if (ov > bestv) { bestv = ov; besti = oi; }
        }
        if ((t & 63) == 0) { wvv[t >> 6] = bestv; wii[t >> 6] = besti; }
        __syncthreads();
        if (t < 64) {
            float b2v = (t < 16) ? wvv[t] : -1.f;
            int   b2i = (t < 16) ? wii[t] : 0;
#pragma unroll
            for (int off = 1; off < 16; off <<= 1) {
                float ov = __shfl_xor(b2v, off, 64);
                int   oi = __shfl_xor(b2i, off, 64);
                if (ov > b2v) { b2v = ov; b2i = oi; }
            }
            if (t == 0) { bi_s = b2i; cidx[r] = b2i; v[b2i] = -2.f; }
        }
        __syncthreads();
    }
    if (t < NCAND) {
        int j = cidx[t];
        ct1[t] = t1a[j];
        cx1[t] = x1[j];
        cx2[t] = x2[j];
    }
    if (t == 0) {
        int j = cidx[NCAND - 1];
        ubx[0] = x1[j];
        ubx[1] = x2[j];
    }
}

// ---------------- kernel 4: classify rows; write easy rows (one wave per row) ----------------
__global__ __launch_bounds__(256) void classify_kernel(
    const float* __restrict__ Wh, const float* __restrict__ params,
    const int* __restrict__ adj, const int* __restrict__ cidx,
    const float* __restrict__ ct1, const float* __restrict__ cx1, const float* __restrict__ cx2,
    const float* __restrict__ ubx, const float* __restrict__ w1, const float* __restrict__ w2,
    const float* __restrict__ nrm, const unsigned* __restrict__ gmaxbits,
    int* __restrict__ hardcnt, int* __restrict__ hardlist, float* __restrict__ out) {
    const int i = (blockIdx.x << 2) + (threadIdx.x >> 6);   // one 64-lane wave per row
    const int lane = threadIdx.x & 63;

    int   cj  = cidx[lane];
    float cT  = ct1[lane];
    float cX1 = cx1[lane];
    float cX2 = cx2[lane];
    int ad = adj[(long long)i * N + cj];
    unsigned long long m = __ballot(ad > 0);

    float w1i = w1[i], w2i = w2[i];
    bool hard = false;
    int j1 = -1;
    if (m == 0ull) {
        hard = true;   // no adjacent candidate (incl. all-zero adj row) -> exact fallback
    } else {
        int f = __ffsll(m) - 1;
        j1 = __shfl(cj, f, 64);
        float t1f = __shfl(cT, f, 64);
        float x1f = __shfl(cX1, f, 64);
        float x2f = __shfl(cX2, f, 64);
        // tie on t1 bits among adjacent candidates -> reference may average -> fallback
        unsigned long long tm = __ballot(ad > 0 && (cT == t1f));
        if (__popcll(tm) > 1) hard = true;
        float Lx1 = w1i * x1f + w2i * x2f;
        unsigned long long m2 = m & ~(1ull << f);
        float Lx2 = -INFINITY;
        if (m2 != 0ull) {
            int s2 = __ffsll(m2) - 1;
            Lx2 = w1i * __shfl(cX1, s2, 64) + w2i * __shfl(cX2, s2, 64);
        }
        float ub  = w1i * ubx[0] + w2i * ubx[1];   // bound for ALL non-candidate columns
        float alt = fmaxf(Lx2, ub);
        float gmax = __uint_as_float(*gmaxbits);
        // |a*G| <= a*|Wh_i|*|Wh_j| both sides; + slack for f32 rounding & our-vs-ref exp diffs
        float margin = 2.0f * params[0] * nrm[i] * gmax + 100.0f + 1e-5f * Lx1;
        if (!(Lx1 - alt > margin)) hard = true;    // NaN-safe: NaN -> hard
    }
    if (hard) {
        if (lane == 0) { int p = atomicAdd(hardcnt, 1); hardlist[p] = i; }
        return;
    }
    // easy: softmax is exactly one-hot at j1 -> out = ELU(Wh[j1])
    float4 v = ((const float4*)&Wh[(long long)j1 * FOUT])[lane];
    v.x = v.x > 0.f ? v.x : expm1f(v.x);
    v.y = v.y > 0.f ? v.y : expm1f(v.y);
    v.z = v.z > 0.f ? v.z : expm1f(v.z);
    v.w = v.w > 0.f ? v.w : expm1f(v.w);
    ((float4*)&out[(long long)i * FOUT])[lane] = v;
}

// ---------------- kernel 5: exact fallback for hard rows (block per row) ----------------
__global__ __launch_bounds__(256) void hardrow_kernel(
    const float* __restrict__ Wh, const float* __restrict__ params,
    const int* __restrict__ adj, const float* __restrict__ x1, const float* __restrict__ x2,
    const float* __restrict__ w1, const float* __restrict__ w2,
    const int* __restrict__ hardcnt, const int* __restrict__ hardlist,
    float* __restrict__ out) {
    __shared__ float Whi[FOUT];
    __shared__ float ebuf[N];     // 32 KB: full logit row
    __shared__ float red[16];
    const int t = threadIdx.x;
    const int nh = *hardcnt;
    for (int h = blockIdx.x; h < nh; h += gridDim.x) {
        const int i = hardlist[h];
        __syncthreads();
        Whi[t] = Wh[(long long)i * FOUT + t];
        __syncthreads();
        const float aC = params[0], cA = params[1], w1i = w1[i], w2i = w2[i];
        const float4* wi4 = (const float4*)Whi;
        for (int j0 = 0; j0 < N; j0 += 256) {
            int j = j0 + t;
            const float4* wr = (const float4*)&Wh[(long long)j * FOUT];
            float s = 0.f;
#pragma unroll 8
            for (int f = 0; f < 64; ++f) {
                float4 a = wi4[f], b = wr[f];
                s = fmaf(a.x, b.x, fmaf(a.y, b.y, fmaf(a.z, b.z, fmaf(a.w, b.w, s))));
            }
            // EXACT same logit assembly as the verified R2 kernel
            float ev = fmaf(aC, s, cA);
            ev = fmaf(w1i, x1[j], ev);
            ev = fmaf(w2i, x2[j], ev);
            ebuf[j] = (adj[(long long)i * N + j] > 0) ? ev : NEGV;
        }
        __syncthreads();
        float mx = -INFINITY;
        for (int j = t; j < N; j += 256) mx = fmaxf(mx, ebuf[j]);
#pragma unroll
        for (int off = 1; off < 64; off <<= 1) mx = fmaxf(mx, __shfl_xor(mx, off, 64));
        if ((t & 63) == 0) red[t >> 6] = mx;
        __syncthreads();
        mx = fmaxf(fmaxf(red[0], red[1]), fmaxf(red[2], red[3]));
        float ls = 0.f;
        for (int j = t; j < N; j += 256) {
            float p = expf(ebuf[j] - mx);
            ebuf[j] = p;
            ls += p;
        }
#pragma unroll
        for (int off = 1; off < 64; off <<= 1) ls += __shfl_xor(ls, off, 64);
        if ((t & 63) == 0) red[8 + (t >> 6)] = ls;
        __syncthreads();
        ls = (red[8] + red[9]) + (red[10] + red[11]);
        float o0 = 0.f, o1 = 0.f, o2 = 0.f, o3 = 0.f;
        for (int j = 0; j < N; j += 4) {
            o0 = fmaf(ebuf[j + 0], Wh[(long long)(j + 0) * FOUT + t], o0);
            o1 = fmaf(ebuf[j + 1], Wh[(long long)(j + 1) * FOUT + t], o1);
            o2 = fmaf(ebuf[j + 2], Wh[(long long)(j + 2) * FOUT + t], o2);
            o3 = fmaf(ebuf[j + 3], Wh[(long long)(j + 3) * FOUT + t], o3);
        }
        float o = ((o0 + o1) + (o2 + o3)) / ls;
        out[(long long)i * FOUT + t] = o > 0.f ? o : expm1f(o);
    }
}

// ---------------- launch ----------------
extern "C" void kernel_launch(void* const* d_in, const int* in_sizes, int n_in,
                              void* d_out, int out_size, void* d_ws, size_t ws_size,
                              hipStream_t stream) {
    const float* h   = (const float*)d_in[0];
    const float* W   = (const float*)d_in[1];
    const float* Mui = (const float*)d_in[2];
    const int*   adj = (const int*)d_in[3];
    float* out = (float*)d_out;

    float* ws = (float*)d_ws;
    float* Wh     = ws;                         // 8192*256
    float* t1a    = Wh + N * FOUT;              // N
    float* x1     = t1a + N;
    float* x2     = x1 + N;
    float* w1     = x2 + N;
    float* w2     = w1 + N;
    float* nrm    = w2 + N;
    float* params = nrm + N;                    // 8
    float* ct1    = params + 8;                 // 64
    float* cx1    = ct1 + NCAND;
    float* cx2    = cx1 + NCAND;
    float* ubx    = cx2 + NCAND;                // 2
    int*   cidx     = (int*)(ubx + 2);          // 64
    int*   hardcnt  = cidx + NCAND;             // 1
    unsigned* gmaxb = (unsigned*)(hardcnt + 1); // 1
    int*   hardlist = (int*)(gmaxb + 1);        // N

    params_kernel<<<1, 64, 0, stream>>>(Mui, params, gmaxb);
    wh_gemm<<<dim3(FOUT / 64, N / 64), 256, 0, stream>>>(h, W, Wh);
    factors2_kernel<<<N, 64, 0, stream>>>(Wh, params, t1a, x1, x2, w1, w2, nrm, gmaxb);
    topk_kernel<<<1, 1024, 0, stream>>>(t1a, x1, x2, cidx, ct1, cx1, cx2, ubx, hardcnt);
    classify_kernel<<<N / 4, 256, 0, stream>>>(Wh, params, adj, cidx, ct1, cx1, cx2, ubx,
                                               w1, w2, nrm, gmaxb, hardcnt, hardlist, out);
    hardrow_kernel<<<128, 256, 0, stream>>>(Wh, params, adj, x1, x2, w1, w2,
                                            hardcnt, hardlist, out);
    (void)n_in; (void)in_sizes; (void)out_size; (void)ws_size;
}

// Round 4
// 503.873 us; speedup vs baseline: 5.2951x; 1.8851x over previous
//
#include <hip/hip_runtime.h>
#include <math.h>

#define N 8192
#define FIN 512
#define FOUT 256
#define NEGV (-9e15f)
#define NCAND 16
#define HMAX 16

typedef long long ll;

// ---------------- kernel 0: mui softmax + derived params (+zero ctrl) ----------------
__global__ void params_kernel(const float* __restrict__ Mui, float* __restrict__ params,
                              unsigned* __restrict__ gmaxbits) {
    if (threadIdx.x == 0) {
        float m = Mui[0];
        for (int i = 1; i < 6; ++i) m = fmaxf(m, Mui[i]);
        float e[6], s = 0.f;
        for (int i = 0; i < 6; ++i) { e[i] = expf(Mui[i] - m); s += e[i]; }
        float mui[6];
        for (int i = 0; i < 6; ++i) mui[i] = e[i] / s;
        params[0] = mui[0] + mui[1] + mui[2] + mui[3];                    // a (G coefficient)
        params[1] = 0.5f * (mui[0] + mui[1]) + 1.0f * (mui[2] + mui[3]); // additive const
        params[2] = 256.0f * mui[4];                                      // D*mui4
        params[3] = 256.0f * mui[5];                                      // D*mui5
        *gmaxbits = 0u;                                                   // re-init every call
    }
}

// ---------------- kernel 1: Wh = h @ W  (8192x512x256 f32) ----------------
#define GK 16
__global__ __launch_bounds__(256) void wh_gemm(const float* __restrict__ A,
                                               const float* __restrict__ B,
                                               float* __restrict__ C) {
    __shared__ float As[GK][68];
    __shared__ float Bs[GK][68];
    const int tid = threadIdx.x;
    const int m0 = blockIdx.y * 64, n0 = blockIdx.x * 64;
    const int tx = tid & 15, ty = tid >> 4;
    const int arow = tid >> 2, akk = (tid & 3) * 4;
    const int brow = tid >> 4, bnn = (tid & 15) * 4;
    float acc[4][4] = {};
    for (int k0 = 0; k0 < FIN; k0 += GK) {
        float4 av = *(const float4*)&A[(m0 + arow) * FIN + k0 + akk];
        float4 bv = *(const float4*)&B[(k0 + brow) * FOUT + n0 + bnn];
        As[akk + 0][arow] = av.x; As[akk + 1][arow] = av.y;
        As[akk + 2][arow] = av.z; As[akk + 3][arow] = av.w;
        *(float4*)&Bs[brow][bnn] = bv;
        __syncthreads();
#pragma unroll
        for (int k = 0; k < GK; ++k) {
            float4 a = *(const float4*)&As[k][4 * ty];
            float4 b = *(const float4*)&Bs[k][4 * tx];
            float ar[4] = {a.x, a.y, a.z, a.w};
            float br[4] = {b.x, b.y, b.z, b.w};
#pragma unroll
            for (int i = 0; i < 4; ++i)
#pragma unroll
                for (int j = 0; j < 4; ++j)
                    acc[i][j] = fmaf(ar[i], br[j], acc[i][j]);
        }
        __syncthreads();
    }
#pragma unroll
    for (int i = 0; i < 4; ++i) {
        float4 v = make_float4(acc[i][0], acc[i][1], acc[i][2], acc[i][3]);
        *(float4*)&C[(m0 + 4 * ty + i) * FOUT + n0 + 4 * tx] = v;
    }
}

// ---------------- kernel 2: per-row factors, t1, row norms, global max norm ----------------
__global__ __launch_bounds__(64) void factors2_kernel(
    const float* __restrict__ Wh, const float* __restrict__ params,
    float* __restrict__ t1a, float* __restrict__ x1, float* __restrict__ x2,
    float* __restrict__ w1, float* __restrict__ w2,
    float* __restrict__ nrm, unsigned* __restrict__ gmaxbits) {
    int i = blockIdx.x;
    int l = threadIdx.x;
    float4 v = ((const float4*)&Wh[i * FOUT])[l];
    float s = v.x * v.x + v.y * v.y + v.z * v.z + v.w * v.w;
#pragma unroll
    for (int off = 1; off < 64; off <<= 1) s += __shfl_xor(s, off, 64);
    if (l == 0) {
        float nr = sqrtf(s);
        nrm[i] = nr;
        atomicMax(gmaxbits, __float_as_uint(nr));   // nr > 0 -> bit-monotone
        float t = Wh[i * FOUT + 1];
        float t1 = t * t;                            // exact same expr as verified R2 kernel
        t1a[i] = t1;
        x1[i] = expf(0.5f * t1);
        x2[i] = expf(t1);
        w1[i] = params[2] * expf(-0.5f * t1);
        w2[i] = params[3] * expf(-t1);
    }
}

// ---------------- kernel 3: top-NCAND t1 columns (single block) ----------------
__global__ __launch_bounds__(1024) void topk_kernel(
    const float* __restrict__ t1a, const float* __restrict__ x1, const float* __restrict__ x2,
    int* __restrict__ cidx, float* __restrict__ ct1, float* __restrict__ cx1,
    float* __restrict__ cx2, float* __restrict__ ubx, int* __restrict__ hardcnt) {
    __shared__ float v[N];
    __shared__ float wvv[16];
    __shared__ int wii[16];
    int t = threadIdx.x;
    for (int k = t; k < N; k += 1024) v[k] = t1a[k];
    if (t == 0) *hardcnt = 0;
    __syncthreads();
    for (int r = 0; r < NCAND; ++r) {
        float bestv = -1.f; int besti = 0;          // t1 >= 0, removed = -2
        for (int k = t; k < N; k += 1024) {
            float x = v[k];
            if (x > bestv) { bestv = x; besti = k; }
        }
#pragma unroll
        for (int off = 1; off < 64; off <<= 1) {
            float ov = __shfl_xor(bestv, off, 64);
            int   oi = __shfl_xor(besti, off, 64);
            if (ov > bestv) { bestv = ov; besti = oi; }
        }
        if ((t & 63) == 0) { wvv[t >> 6] = bestv; wii[t >> 6] = besti; }
        __syncthreads();
        if (t < 64) {
            float b2v = (t < 16) ? wvv[t] : -1.f;
            int   b2i = (t < 16) ? wii[t] : 0;
#pragma unroll
            for (int off = 1; off < 16; off <<= 1) {
                float ov = __shfl_xor(b2v, off, 64);
                int   oi = __shfl_xor(b2i, off, 64);
                if (ov > b2v) { b2v = ov; b2i = oi; }
            }
            if (t == 0) { cidx[r] = b2i; v[b2i] = -2.f; }
        }
        __syncthreads();
    }
    if (t < NCAND) {
        int j = cidx[t];
        ct1[t] = t1a[j];
        cx1[t] = x1[j];
        cx2[t] = x2[j];
    }
    if (t == 0) {
        int j = cidx[NCAND - 1];
        ubx[0] = x1[j];
        ubx[1] = x2[j];
    }
}

// ---------------- kernel 3b: init hard-row accumulators ----------------
__global__ __launch_bounds__(256) void hardinit_kernel(float* __restrict__ acc,
                                                       float* __restrict__ rowsum,
                                                       unsigned* __restrict__ rowmaxenc) {
    int b = blockIdx.x, t = threadIdx.x;
    acc[b * FOUT + t] = 0.f;
    if (t == 0) { rowsum[b] = 0.f; rowmaxenc[b] = 0u; }
}

// ---------------- kernel 4: classify rows; write easy rows (one wave per row) ----------------
__global__ __launch_bounds__(256) void classify_kernel(
    const float* __restrict__ Wh, const float* __restrict__ params,
    const int* __restrict__ adj, const int* __restrict__ cidx,
    const float* __restrict__ ct1, const float* __restrict__ cx1, const float* __restrict__ cx2,
    const float* __restrict__ ubx, const float* __restrict__ w1, const float* __restrict__ w2,
    const float* __restrict__ nrm, const unsigned* __restrict__ gmaxbits,
    int* __restrict__ hardcnt, int* __restrict__ hardlist, float* __restrict__ out) {
    const int i = (blockIdx.x << 2) + (threadIdx.x >> 6);   // one 64-lane wave per row
    const int lane = threadIdx.x & 63;
    const bool valid = lane < NCAND;

    int   cj  = valid ? cidx[lane] : 0;
    float cT  = valid ? ct1[lane] : -1.f;
    float cX1 = valid ? cx1[lane] : 0.f;
    float cX2 = valid ? cx2[lane] : 0.f;
    int ad = valid ? adj[(ll)i * N + cj] : 0;
    unsigned long long m = __ballot(ad > 0);

    float w1i = w1[i], w2i = w2[i];
    bool hard = false;
    int j1 = -1;
    if (m == 0ull) {
        hard = true;   // no adjacent candidate (incl. all-zero adj row) -> exact fallback
    } else {
        int f = __ffsll(m) - 1;
        j1 = __shfl(cj, f, 64);
        float t1f = __shfl(cT, f, 64);
        float x1f = __shfl(cX1, f, 64);
        float x2f = __shfl(cX2, f, 64);
        float lastT = __shfl(cT, NCAND - 1, 64);
        // tie on t1 bits among adjacent candidates -> reference may average -> fallback;
        // tie with the candidate-list boundary value -> off-list tie possible -> fallback
        unsigned long long tm = __ballot(ad > 0 && (cT == t1f));
        if (__popcll(tm) > 1 || t1f == lastT) hard = true;
        float Lx1 = w1i * x1f + w2i * x2f;
        unsigned long long m2 = m & ~(1ull << f);
        float Lx2 = -INFINITY;
        if (m2 != 0ull) {
            int s2 = __ffsll(m2) - 1;
            Lx2 = w1i * __shfl(cX1, s2, 64) + w2i * __shfl(cX2, s2, 64);
        }
        float ub  = w1i * ubx[0] + w2i * ubx[1];   // bound for ALL non-candidate columns
        float alt = fmaxf(Lx2, ub);
        float gmax = __uint_as_float(*gmaxbits);
        // |a*G| <= a*|Wh_i|*|Wh_j| both sides; + slack for f32 rounding & our-vs-ref exp diffs
        float margin = 2.0f * params[0] * nrm[i] * gmax + 100.0f + 1e-5f * Lx1;
        if (!(Lx1 - alt > margin)) hard = true;    // NaN-safe: NaN -> hard
    }
    if (hard) {
        if (lane == 0) { int p = atomicAdd(hardcnt, 1); hardlist[p] = i; }
        return;
    }
    // easy: softmax is exactly one-hot at j1 -> out = ELU(Wh[j1])
    float4 v = ((const float4*)&Wh[(ll)j1 * FOUT])[lane];
    v.x = v.x > 0.f ? v.x : expm1f(v.x);
    v.y = v.y > 0.f ? v.y : expm1f(v.y);
    v.z = v.z > 0.f ? v.z : expm1f(v.z);
    v.w = v.w > 0.f ? v.w : expm1f(v.w);
    ((float4*)&out[(ll)i * FOUT])[lane] = v;
}

// ---------------- kernel 5a: hard rows — logits + row max (parallel over chunks) ----------------
__global__ __launch_bounds__(256) void hardA_kernel(
    const float* __restrict__ Wh, const float* __restrict__ params,
    const int* __restrict__ adj, const float* __restrict__ x1, const float* __restrict__ x2,
    const float* __restrict__ w1, const float* __restrict__ w2,
    const int* __restrict__ hardcnt, const int* __restrict__ hardlist,
    float* __restrict__ ebuf, unsigned* __restrict__ rowmaxenc) {
    const int h = blockIdx.x >> 5;          // 32 chunks of 256 columns
    const int chunk = blockIdx.x & 31;
    const int nh = min(*hardcnt, HMAX);
    if (h >= nh) return;
    const int i = hardlist[h];
    __shared__ float Whi[FOUT];
    __shared__ float red[4];
    const int t = threadIdx.x;
    Whi[t] = Wh[(ll)i * FOUT + t];
    __syncthreads();
    const int j = (chunk << 8) + t;
    const float4* wi4 = (const float4*)Whi;
    const float4* wr  = (const float4*)&Wh[(ll)j * FOUT];
    float s = 0.f;
#pragma unroll 8
    for (int f = 0; f < 64; ++f) {
        float4 a = wi4[f], b = wr[f];
        s = fmaf(a.x, b.x, fmaf(a.y, b.y, fmaf(a.z, b.z, fmaf(a.w, b.w, s))));
    }
    // EXACT same logit assembly as the verified R2 kernel
    float ev = fmaf(params[0], s, params[1]);
    ev = fmaf(w1[i], x1[j], ev);
    ev = fmaf(w2[i], x2[j], ev);
    ev = (adj[(ll)i * N + j] > 0) ? ev : NEGV;
    ebuf[h * N + j] = ev;
    float mx = ev;
#pragma unroll
    for (int off = 1; off < 64; off <<= 1) mx = fmaxf(mx, __shfl_xor(mx, off, 64));
    if ((t & 63) == 0) red[t >> 6] = mx;
    __syncthreads();
    if (t == 0) {
        mx = fmaxf(fmaxf(red[0], red[1]), fmaxf(red[2], red[3]));
        unsigned u = __float_as_uint(mx);
        unsigned enc = (u & 0x80000000u) ? ~u : (u | 0x80000000u);
        atomicMax(&rowmaxenc[h], enc);
    }
}

// ---------------- kernel 5b: hard rows — exp/sum + partial PV ----------------
__global__ __launch_bounds__(256) void hardB_kernel(
    const float* __restrict__ Wh, const int* __restrict__ hardcnt,
    const float* __restrict__ ebuf, const unsigned* __restrict__ rowmaxenc,
    float* __restrict__ rowsum, float* __restrict__ acc) {
    const int h = blockIdx.x >> 5;
    const int chunk = blockIdx.x & 31;
    const int nh = min(*hardcnt, HMAX);
    if (h >= nh) return;
    const int t = threadIdx.x;
    unsigned enc = rowmaxenc[h];
    unsigned u = (enc & 0x80000000u) ? (enc & 0x7fffffffu) : ~enc;
    const float mx = __uint_as_float(u);
    const int j = (chunk << 8) + t;
    float p = expf(ebuf[h * N + j] - mx);
    __shared__ float pl[256];
    pl[t] = p;
    float ps = p;
#pragma unroll
    for (int off = 1; off < 64; off <<= 1) ps += __shfl_xor(ps, off, 64);
    if ((t & 63) == 0) atomicAdd(&rowsum[h], ps);
    __syncthreads();
    float o = 0.f;
    const float* base = &Wh[(ll)(chunk << 8) * FOUT + t];
#pragma unroll 4
    for (int jj = 0; jj < 256; ++jj) o = fmaf(pl[jj], base[(ll)jj * FOUT], o);
    atomicAdd(&acc[h * FOUT + t], o);
}

// ---------------- kernel 5c: hard rows — normalize + ELU + store ----------------
__global__ __launch_bounds__(256) void hardC_kernel(
    const int* __restrict__ hardcnt, const int* __restrict__ hardlist,
    const float* __restrict__ rowsum, const float* __restrict__ acc,
    float* __restrict__ out) {
    const int h = blockIdx.x;
    const int nh = min(*hardcnt, HMAX);
    if (h >= nh) return;
    const int i = hardlist[h];
    const int t = threadIdx.x;
    float o = acc[h * FOUT + t] / rowsum[h];
    out[(ll)i * FOUT + t] = o > 0.f ? o : expm1f(o);
}

// ---------------- kernel 5d: serial overflow fallback (h >= HMAX; normally no-op) ----------------
__global__ __launch_bounds__(256) void hardtail_kernel(
    const float* __restrict__ Wh, const float* __restrict__ params,
    const int* __restrict__ adj, const float* __restrict__ x1, const float* __restrict__ x2,
    const float* __restrict__ w1, const float* __restrict__ w2,
    const int* __restrict__ hardcnt, const int* __restrict__ hardlist,
    float* __restrict__ out) {
    __shared__ float Whi[FOUT];
    __shared__ float ebuf[N];
    __shared__ float red[16];
    const int t = threadIdx.x;
    const int nh = *hardcnt;
    for (int h = HMAX + blockIdx.x; h < nh; h += gridDim.x) {
        const int i = hardlist[h];
        __syncthreads();
        Whi[t] = Wh[(ll)i * FOUT + t];
        __syncthreads();
        const float aC = params[0], cA = params[1], w1i = w1[i], w2i = w2[i];
        const float4* wi4 = (const float4*)Whi;
        for (int j0 = 0; j0 < N; j0 += 256) {
            int j = j0 + t;
            const float4* wr = (const float4*)&Wh[(ll)j * FOUT];
            float s = 0.f;
#pragma unroll 8
            for (int f = 0; f < 64; ++f) {
                float4 a = wi4[f], b = wr[f];
                s = fmaf(a.x, b.x, fmaf(a.y, b.y, fmaf(a.z, b.z, fmaf(a.w, b.w, s))));
            }
            float ev = fmaf(aC, s, cA);
            ev = fmaf(w1i, x1[j], ev);
            ev = fmaf(w2i, x2[j], ev);
            ebuf[j] = (adj[(ll)i * N + j] > 0) ? ev : NEGV;
        }
        __syncthreads();
        float mx = -INFINITY;
        for (int j = t; j < N; j += 256) mx = fmaxf(mx, ebuf[j]);
#pragma unroll
        for (int off = 1; off < 64; off <<= 1) mx = fmaxf(mx, __shfl_xor(mx, off, 64));
        if ((t & 63) == 0) red[t >> 6] = mx;
        __syncthreads();
        mx = fmaxf(fmaxf(red[0], red[1]), fmaxf(red[2], red[3]));
        float ls = 0.f;
        for (int j = t; j < N; j += 256) {
            float p = expf(ebuf[j] - mx);
            ebuf[j] = p;
            ls += p;
        }
#pragma unroll
        for (int off = 1; off < 64; off <<= 1) ls += __shfl_xor(ls, off, 64);
        if ((t & 63) == 0) red[8 + (t >> 6)] = ls;
        __syncthreads();
        ls = (red[8] + red[9]) + (red[10] + red[11]);
        float o0 = 0.f, o1 = 0.f, o2 = 0.f, o3 = 0.f;
        for (int j = 0; j < N; j += 4) {
            o0 = fmaf(ebuf[j + 0], Wh[(ll)(j + 0) * FOUT + t], o0);
            o1 = fmaf(ebuf[j + 1], Wh[(ll)(j + 1) * FOUT + t], o1);
            o2 = fmaf(ebuf[j + 2], Wh[(ll)(j + 2) * FOUT + t], o2);
            o3 = fmaf(ebuf[j + 3], Wh[(ll)(j + 3) * FOUT + t], o3);
        }
        float o = ((o0 + o1) + (o2 + o3)) / ls;
        out[(ll)i * FOUT + t] = o > 0.f ? o : expm1f(o);
    }
}

// ---------------- launch ----------------
extern "C" void kernel_launch(void* const* d_in, const int* in_sizes, int n_in,
                              void* d_out, int out_size, void* d_ws, size_t ws_size,
                              hipStream_t stream) {
    const float* h   = (const float*)d_in[0];
    const float* W   = (const float*)d_in[1];
    const float* Mui = (const float*)d_in[2];
    const int*   adj = (const int*)d_in[3];
    float* out = (float*)d_out;

    float* ws = (float*)d_ws;
    float* Wh     = ws;                         // 8192*256
    float* t1a    = Wh + N * FOUT;              // N
    float* x1     = t1a + N;
    float* x2     = x1 + N;
    float* w1     = x2 + N;
    float* w2     = w1 + N;
    float* nrm    = w2 + N;
    float* params = nrm + N;                    // 8
    float* ct1    = params + 8;                 // NCAND
    float* cx1    = ct1 + NCAND;
    float* cx2    = cx1 + NCAND;
    float* ubx    = cx2 + NCAND;                // 2
    float* ebuf   = ubx + 2;                    // HMAX*N
    float* acc    = ebuf + HMAX * N;            // HMAX*FOUT
    float* rowsum = acc + HMAX * FOUT;          // HMAX
    int*   cidx      = (int*)(rowsum + HMAX);   // NCAND
    int*   hardcnt   = cidx + NCAND;            // 1
    unsigned* gmaxb  = (unsigned*)(hardcnt + 1);// 1
    unsigned* rowmaxenc = gmaxb + 1;            // HMAX
    int*   hardlist  = (int*)(rowmaxenc + HMAX);// N

    params_kernel<<<1, 64, 0, stream>>>(Mui, params, gmaxb);
    wh_gemm<<<dim3(FOUT / 64, N / 64), 256, 0, stream>>>(h, W, Wh);
    factors2_kernel<<<N, 64, 0, stream>>>(Wh, params, t1a, x1, x2, w1, w2, nrm, gmaxb);
    topk_kernel<<<1, 1024, 0, stream>>>(t1a, x1, x2, cidx, ct1, cx1, cx2, ubx, hardcnt);
    hardinit_kernel<<<HMAX, 256, 0, stream>>>(acc, rowsum, rowmaxenc);
    classify_kernel<<<N / 4, 256, 0, stream>>>(Wh, params, adj, cidx, ct1, cx1, cx2, ubx,
                                               w1, w2, nrm, gmaxb, hardcnt, hardlist, out);
    hardA_kernel<<<32 * HMAX, 256, 0, stream>>>(Wh, params, adj, x1, x2, w1, w2,
                                                hardcnt, hardlist, ebuf, rowmaxenc);
    hardB_kernel<<<32 * HMAX, 256, 0, stream>>>(Wh, hardcnt, ebuf, rowmaxenc, rowsum, acc);
    hardC_kernel<<<HMAX, 256, 0, stream>>>(hardcnt, hardlist, rowsum, acc, out);
    hardtail_kernel<<<128, 256, 0, stream>>>(Wh, params, adj, x1, x2, w1, w2,
                                             hardcnt, hardlist, out);
    (void)n_in; (void)in_sizes; (void)out_size; (void)ws_size;
}